// Round 1
// baseline (105.159 us; speedup 1.0000x reference)
//
#include <hip/hip_runtime.h>

#define BHN (16 * 2048)   // rows
#define NN  2048          // row length
#define CC  64
#define TT  64

__global__ __launch_bounds__(256, 4) void cope_kernel(
    const float* __restrict__ q,
    const float* __restrict__ qk,
    const float* __restrict__ pos_emb,
    float* __restrict__ out)
{
    const int row  = blockIdx.x;       // [0, BH*N)
    const int tid  = threadIdx.x;      // [0, 256)
    const int lane = tid & 63;
    const int wv   = tid >> 6;

    __shared__ float q_lds[CC];
    __shared__ float e_part[4][TT];
    __shared__ float e_row[TT];
    __shared__ float wave_tot[4];

    const size_t rowN = (size_t)row * NN;

    // ---- issue the qk row loads EARLY (latency hidden under E compute) ----
    const float4* qk4 = (const float4*)(qk + rowN);
    float4 v0 = qk4[tid * 2];
    float4 v1 = qk4[tid * 2 + 1];

    // ---- stage q row (64 floats) ----
    if (tid < CC) q_lds[tid] = q[(size_t)row * CC + tid];
    __syncthreads();

    // ---- E[t] = sum_c q[c] * pos_emb[c][t], split c into 4 quarters ----
    {
        const int t  = tid & 63;
        const int c0 = (tid >> 6) * 16;
        float acc = 0.0f;
#pragma unroll
        for (int cc = 0; cc < 16; ++cc)
            acc = fmaf(q_lds[c0 + cc], pos_emb[(c0 + cc) * TT + t], acc);
        e_part[tid >> 6][t] = acc;
    }
    __syncthreads();
    if (tid < TT)
        e_row[tid] = e_part[0][tid] + e_part[1][tid] + e_part[2][tid] + e_part[3][tid];

    // ---- sigmoid of my 8 elements ----
    float g[8];
    g[0] = v0.x; g[1] = v0.y; g[2] = v0.z; g[3] = v0.w;
    g[4] = v1.x; g[5] = v1.y; g[6] = v1.z; g[7] = v1.w;
#pragma unroll
    for (int k = 0; k < 8; ++k)
        g[k] = 1.0f / (1.0f + __expf(-g[k]));

    // ---- thread chunk sum ----
    float s = 0.0f;
#pragma unroll
    for (int k = 0; k < 8; ++k) s += g[k];

    // ---- wave-level inclusive suffix scan over 64 lanes ----
    float inc = s;
#pragma unroll
    for (int o = 1; o < 64; o <<= 1) {
        float tmp = __shfl_down(inc, o, 64);
        if (lane + o < 64) inc += tmp;
    }
    const float X = inc - s;                 // exclusive suffix within wave
    if (lane == 0) wave_tot[wv] = inc;       // wave total (lane 0 holds it)
    __syncthreads();                          // publishes wave_tot AND e_row

    float W = 0.0f;
#pragma unroll
    for (int w2 = 0; w2 < 4; ++w2)
        if (w2 > wv) W += wave_tot[w2];
    const float base = X + W;

    // ---- local running suffix, clamp, gather-interp ----
    float o8[8];
    float run = 0.0f;
#pragma unroll
    for (int k = 7; k >= 0; --k) {
        run += g[k];
        float P  = fminf(run + base, 63.0f);
        float fl = floorf(P);
        float w_ = P - fl;
        int   i0 = (int)fl;
        int   i1 = (int)ceilf(P);
        float ef = e_row[i0];
        float ec = e_row[i1];
        o8[k] = fmaf(w_, ec - ef, ef);
    }

    float4* out4 = (float4*)(out + rowN);
    out4[tid * 2]     = make_float4(o8[0], o8[1], o8[2], o8[3]);
    out4[tid * 2 + 1] = make_float4(o8[4], o8[5], o8[6], o8[7]);
}

extern "C" void kernel_launch(void* const* d_in, const int* in_sizes, int n_in,
                              void* d_out, int out_size, void* d_ws, size_t ws_size,
                              hipStream_t stream) {
    const float* q       = (const float*)d_in[0];
    const float* qk      = (const float*)d_in[1];
    const float* pos_emb = (const float*)d_in[2];
    float* out = (float*)d_out;

    dim3 grid(BHN);
    dim3 block(256);
    cope_kernel<<<grid, block, 0, stream>>>(q, qk, pos_emb, out);
}